// Round 1
// baseline (1503.034 us; speedup 1.0000x reference)
//
#include <hip/hip_runtime.h>
#include <stdint.h>

#define ROWLEN   16384
#define NTHREADS 256
#define VPT (ROWLEN / (NTHREADS * 4))   // 16 uint4 per thread

// One block per row. Row staged once in LDS as raw f32 bits; exact k-th
// largest |x| found by 3-round radix select (11+10+10 bits) on the abs bit
// pattern; output written in one coalesced pass. Ties at the threshold are
// resolved lowest-index-first (matches jax.lax.top_k).
__global__ __launch_bounds__(NTHREADS) void topk_abs_kernel(
    const uint32_t* __restrict__ x, const int* __restrict__ kptr,
    uint32_t* __restrict__ out)
{
    __shared__ alignas(16) uint32_t data[ROWLEN];   // 64 KiB: raw value bits
    __shared__ uint32_t hist[2048];                 // 8 KiB: histogram / tie scratch
    __shared__ uint32_t s_prefix;
    __shared__ int s_kk, s_ceq, s_cnt;

    const int tid = threadIdx.x;
    const uint4* __restrict__ xr  = (const uint4*)(x   + (size_t)blockIdx.x * ROWLEN);
    uint4* __restrict__ outr      = (uint4*)      (out + (size_t)blockIdx.x * ROWLEN);
    uint4* dvec = (uint4*)data;
    const int k = *kptr;

    // ---- Phase A: HBM -> LDS, 16 B/lane fully coalesced ----
    #pragma unroll
    for (int i = 0; i < VPT; ++i) {
        int p = i * NTHREADS + tid;
        dvec[p] = xr[p];
    }

    // ---- Phase B: radix select k-th largest abs key (exact, 31 bits) ----
    uint32_t prefix = 0;
    int kk = k;
    const int shifts[3] = {20, 10, 0};
    const int nbits[3]  = {11, 10, 10};

    for (int r = 0; r < 3; ++r) {
        const int shift = shifts[r];
        const int nb = 1 << nbits[r];
        const uint32_t dmask = (uint32_t)(nb - 1);
        __syncthreads();                       // covers phase A / prior round's scan
        for (int b = tid; b < nb; b += NTHREADS) hist[b] = 0u;
        __syncthreads();
        const uint32_t pm = (r == 0) ? 0u : (0xFFFFFFFFu << (shift + nbits[r]));
        #pragma unroll
        for (int i = 0; i < VPT; ++i) {
            uint4 v = dvec[i * NTHREADS + tid];
            uint32_t a;
            a = v.x & 0x7FFFFFFFu; if ((a & pm) == prefix) atomicAdd(&hist[(a >> shift) & dmask], 1u);
            a = v.y & 0x7FFFFFFFu; if ((a & pm) == prefix) atomicAdd(&hist[(a >> shift) & dmask], 1u);
            a = v.z & 0x7FFFFFFFu; if ((a & pm) == prefix) atomicAdd(&hist[(a >> shift) & dmask], 1u);
            a = v.w & 0x7FFFFFFFu; if ((a & pm) == prefix) atomicAdd(&hist[(a >> shift) & dmask], 1u);
        }
        __syncthreads();
        if (tid == 0) {
            int cum = 0, b = nb - 1;
            for (; b > 0; --b) {
                int c = (int)hist[b];
                if (cum + c >= kk) break;
                cum += c;
            }
            s_prefix = prefix | ((uint32_t)b << shift);
            s_kk  = kk - cum;        // rank among keys with the new prefix
            s_ceq = (int)hist[b];    // keys exactly equal (final round: == T count)
        }
        __syncthreads();
        prefix = s_prefix;
        kk = s_kk;
    }

    const uint32_t T = prefix;       // exact k-th largest abs bit pattern
    const int e   = kk;              // how many equals-to-T to keep
    const int ceq = s_ceq;           // how many equals-to-T exist
    const bool rare = (ceq != e);    // tie at the cutoff (≈never on random data)
    int nc = 0;

    if (rare) {
        if (tid == 0) s_cnt = 0;
        __syncthreads();
        #pragma unroll
        for (int i = 0; i < VPT; ++i) {
            int p = i * NTHREADS + tid;
            uint4 v = dvec[p];
            if ((v.x & 0x7FFFFFFFu) == T) { int q = atomicAdd(&s_cnt, 1); if (q < 1024) hist[q] = (uint32_t)(4*p+0); }
            if ((v.y & 0x7FFFFFFFu) == T) { int q = atomicAdd(&s_cnt, 1); if (q < 1024) hist[q] = (uint32_t)(4*p+1); }
            if ((v.z & 0x7FFFFFFFu) == T) { int q = atomicAdd(&s_cnt, 1); if (q < 1024) hist[q] = (uint32_t)(4*p+2); }
            if ((v.w & 0x7FFFFFFFu) == T) { int q = atomicAdd(&s_cnt, 1); if (q < 1024) hist[q] = (uint32_t)(4*p+3); }
        }
        __syncthreads();
        nc = s_cnt; if (nc > 1024) nc = 1024;
        // keep the e smallest indices among the equals (lowest-index tie-break)
        for (int t = tid; t < nc; t += NTHREADS) {
            uint32_t my = hist[t];
            int rank = 0;
            for (int j = 0; j < nc; ++j) rank += (hist[j] < my) ? 1 : 0;
            hist[1024 + t] = (rank < e) ? 1u : 0u;
        }
        __syncthreads();
    }

    // ---- Phase C: LDS -> HBM, threshold + write, 16 B/lane coalesced ----
    #pragma unroll
    for (int i = 0; i < VPT; ++i) {
        int p = i * NTHREADS + tid;
        uint4 v = dvec[p];
        uint4 o;
        {
            uint32_t bits = v.x, key = bits & 0x7FFFFFFFu, res;
            if (key > T) res = bits;
            else if (key < T) res = 0u;
            else if (!rare) res = bits;
            else { res = 0u; for (int j = 0; j < nc; ++j) if (hist[j] == (uint32_t)(4*p+0)) { res = hist[1024+j] ? bits : 0u; break; } }
            o.x = res;
        }
        {
            uint32_t bits = v.y, key = bits & 0x7FFFFFFFu, res;
            if (key > T) res = bits;
            else if (key < T) res = 0u;
            else if (!rare) res = bits;
            else { res = 0u; for (int j = 0; j < nc; ++j) if (hist[j] == (uint32_t)(4*p+1)) { res = hist[1024+j] ? bits : 0u; break; } }
            o.y = res;
        }
        {
            uint32_t bits = v.z, key = bits & 0x7FFFFFFFu, res;
            if (key > T) res = bits;
            else if (key < T) res = 0u;
            else if (!rare) res = bits;
            else { res = 0u; for (int j = 0; j < nc; ++j) if (hist[j] == (uint32_t)(4*p+2)) { res = hist[1024+j] ? bits : 0u; break; } }
            o.z = res;
        }
        {
            uint32_t bits = v.w, key = bits & 0x7FFFFFFFu, res;
            if (key > T) res = bits;
            else if (key < T) res = 0u;
            else if (!rare) res = bits;
            else { res = 0u; for (int j = 0; j < nc; ++j) if (hist[j] == (uint32_t)(4*p+3)) { res = hist[1024+j] ? bits : 0u; break; } }
            o.w = res;
        }
        outr[p] = o;
    }
}

extern "C" void kernel_launch(void* const* d_in, const int* in_sizes, int n_in,
                              void* d_out, int out_size, void* d_ws, size_t ws_size,
                              hipStream_t stream) {
    const uint32_t* x = (const uint32_t*)d_in[0];
    const int* kptr   = (const int*)d_in[1];
    uint32_t* out     = (uint32_t*)d_out;
    const int rows = in_sizes[0] / ROWLEN;   // 4096 rows of 16384
    topk_abs_kernel<<<rows, NTHREADS, 0, stream>>>(x, kptr, out);
}

// Round 2
// 109.715 us; speedup vs baseline: 13.6994x; 13.6994x over previous
//
#include <hip/hip_runtime.h>
#include <stdint.h>

#define ROWLEN 16384
#define NT 512
#define VPT 8   // uint4 per thread: 512 threads * 4 elems * 8 = 16384

// Parallel suffix-scan bin select: finds largest bin b with suffix_count(b) >= kk.
// Writes s_bin (bin), s_kk (rank within bin, from top), s_ceq (count in bin).
// All NT threads must call (contains barriers).
template <int NB>
__device__ __forceinline__ void select_bin(const uint32_t* __restrict__ hist,
                                           uint32_t* __restrict__ s_part,
                                           uint32_t* s_bin, int* s_kk, int* s_ceq,
                                           int kk, int tid)
{
    constexpr int C = NB / NT;   // bins per thread (4 for 2048, 2 for 1024)
    uint32_t s = 0;
    #pragma unroll
    for (int j = 0; j < C; ++j) s += hist[tid * C + j];
    s_part[tid] = s;
    __syncthreads();
    if (tid < 64) {              // wave 0: 64 groups of 8 thread-chunks
        uint32_t g = 0;
        #pragma unroll
        for (int j = 0; j < 8; ++j) g += s_part[tid * 8 + j];
        uint32_t S = g;          // suffix-inclusive scan (descending bins = ascending idx)
        #pragma unroll
        for (int off = 1; off < 64; off <<= 1) {
            uint32_t o = __shfl_down(S, off, 64);
            if (tid + off < 64) S += o;
        }
        unsigned long long m = __ballot(S >= (uint32_t)kk);
        int c = 63 - __builtin_clzll(m);                 // crossing group
        uint32_t hv = __shfl(S, (c + 1) & 63, 64);
        uint32_t higher = (c == 63) ? 0u : hv;           // count in groups above c
        if (tid == 0) {
            uint32_t pp[8];
            #pragma unroll
            for (int j = 0; j < 8; ++j) pp[j] = s_part[c * 8 + j];   // independent loads
            int kk2 = kk - (int)higher;
            int cum = 0, j = 7;
            #pragma unroll
            for (int it = 7; it > 0; --it) {
                int cc = (int)pp[j];
                if (cum + cc >= kk2) break;
                cum += cc; --j;
            }
            int tt = c * 8 + j;
            int kk3 = kk2 - cum;
            uint32_t bb[C];
            #pragma unroll
            for (int jj = 0; jj < C; ++jj) bb[jj] = hist[tt * C + jj];
            int cum2 = 0, b = C - 1;
            #pragma unroll
            for (int it = C - 1; it > 0; --it) {
                int cc = (int)bb[b];
                if (cum2 + cc >= kk3) break;
                cum2 += cc; --b;
            }
            *s_bin = (uint32_t)(tt * C + b);
            *s_kk  = kk3 - cum2;
            *s_ceq = (int)bb[b];
        }
    }
    __syncthreads();
}

__global__ __launch_bounds__(NT) void topk_abs_kernel(
    const uint32_t* __restrict__ x, const int* __restrict__ kptr,
    uint32_t* __restrict__ out)
{
    __shared__ uint32_t hist[2048];   // lower 1024: round-1/2 bins, tie idx; upper 1024: candidates, tie flags
    __shared__ uint32_t s_part[NT];
    __shared__ uint32_t s_bin;
    __shared__ int s_kk, s_ceq, s_cnt;

    const int tid = threadIdx.x;
    const uint4* __restrict__ xr  = (const uint4*)(x   + (size_t)blockIdx.x * ROWLEN);
    uint4* __restrict__ outr      = (uint4*)      (out + (size_t)blockIdx.x * ROWLEN);
    const int k = *kptr;

    // ---- Phase A: HBM -> registers (32 VGPRs), fully coalesced 16 B/lane ----
    uint4 v[VPT];
    #pragma unroll
    for (int i = 0; i < VPT; ++i) v[i] = xr[i * NT + tid];

    // round-0 histogram: 11-bit digit (bits 30:20) over abs bit pattern
    hist[tid] = 0; hist[tid + 512] = 0; hist[tid + 1024] = 0; hist[tid + 1536] = 0;
    __syncthreads();
    #pragma unroll
    for (int i = 0; i < VPT; ++i) {
        atomicAdd(&hist[(v[i].x & 0x7FFFFFFFu) >> 20], 1u);
        atomicAdd(&hist[(v[i].y & 0x7FFFFFFFu) >> 20], 1u);
        atomicAdd(&hist[(v[i].z & 0x7FFFFFFFu) >> 20], 1u);
        atomicAdd(&hist[(v[i].w & 0x7FFFFFFFu) >> 20], 1u);
    }
    __syncthreads();
    select_bin<2048>(hist, s_part, &s_bin, &s_kk, &s_ceq, k, tid);
    const uint32_t b0 = s_bin;
    int kk = s_kk;
    const int ceq0 = s_ceq;

    // clear lower 1024 bins + candidate counter
    hist[tid] = 0; hist[tid + 512] = 0;
    if (tid == 0) s_cnt = 0;
    __syncthreads();

    uint32_t T; int e, ceqT;
    if (ceq0 <= 1024) {
        // ---- candidate path: compact survivors, rounds 1-2 over <=1024 elems ----
        uint32_t* cand = hist + 1024;
        #pragma unroll
        for (int i = 0; i < VPT; ++i) {
            uint32_t a;
            a = v[i].x & 0x7FFFFFFFu; if ((a >> 20) == b0) { cand[atomicAdd(&s_cnt, 1)] = a; atomicAdd(&hist[(a >> 10) & 1023u], 1u); }
            a = v[i].y & 0x7FFFFFFFu; if ((a >> 20) == b0) { cand[atomicAdd(&s_cnt, 1)] = a; atomicAdd(&hist[(a >> 10) & 1023u], 1u); }
            a = v[i].z & 0x7FFFFFFFu; if ((a >> 20) == b0) { cand[atomicAdd(&s_cnt, 1)] = a; atomicAdd(&hist[(a >> 10) & 1023u], 1u); }
            a = v[i].w & 0x7FFFFFFFu; if ((a >> 20) == b0) { cand[atomicAdd(&s_cnt, 1)] = a; atomicAdd(&hist[(a >> 10) & 1023u], 1u); }
        }
        __syncthreads();
        select_bin<1024>(hist, s_part, &s_bin, &s_kk, &s_ceq, kk, tid);
        const uint32_t b1 = s_bin;
        kk = s_kk;
        hist[tid] = 0; hist[tid + 512] = 0;
        __syncthreads();
        for (int t = tid; t < ceq0; t += NT) {
            uint32_t a = cand[t];
            if (((a >> 10) & 1023u) == b1) atomicAdd(&hist[a & 1023u], 1u);
        }
        __syncthreads();
        select_bin<1024>(hist, s_part, &s_bin, &s_kk, &s_ceq, kk, tid);
        T = (b0 << 20) | (b1 << 10) | s_bin;
        e = s_kk; ceqT = s_ceq;
    } else {
        // ---- fallback (pathological skew): full-data rounds from registers ----
        #pragma unroll
        for (int i = 0; i < VPT; ++i) {
            uint32_t a;
            a = v[i].x & 0x7FFFFFFFu; if ((a >> 20) == b0) atomicAdd(&hist[(a >> 10) & 1023u], 1u);
            a = v[i].y & 0x7FFFFFFFu; if ((a >> 20) == b0) atomicAdd(&hist[(a >> 10) & 1023u], 1u);
            a = v[i].z & 0x7FFFFFFFu; if ((a >> 20) == b0) atomicAdd(&hist[(a >> 10) & 1023u], 1u);
            a = v[i].w & 0x7FFFFFFFu; if ((a >> 20) == b0) atomicAdd(&hist[(a >> 10) & 1023u], 1u);
        }
        __syncthreads();
        select_bin<1024>(hist, s_part, &s_bin, &s_kk, &s_ceq, kk, tid);
        const uint32_t b1 = s_bin;
        kk = s_kk;
        hist[tid] = 0; hist[tid + 512] = 0;
        __syncthreads();
        const uint32_t pfx = (b0 << 10) | b1;
        #pragma unroll
        for (int i = 0; i < VPT; ++i) {
            uint32_t a;
            a = v[i].x & 0x7FFFFFFFu; if ((a >> 10) == pfx) atomicAdd(&hist[a & 1023u], 1u);
            a = v[i].y & 0x7FFFFFFFu; if ((a >> 10) == pfx) atomicAdd(&hist[a & 1023u], 1u);
            a = v[i].z & 0x7FFFFFFFu; if ((a >> 10) == pfx) atomicAdd(&hist[a & 1023u], 1u);
            a = v[i].w & 0x7FFFFFFFu; if ((a >> 10) == pfx) atomicAdd(&hist[a & 1023u], 1u);
        }
        __syncthreads();
        select_bin<1024>(hist, s_part, &s_bin, &s_kk, &s_ceq, kk, tid);
        T = (b0 << 20) | (b1 << 10) | s_bin;
        e = s_kk; ceqT = s_ceq;
    }

    // ---- tie at the cutoff (≈never on random data): lowest-index-first ----
    const bool rare = (ceqT != e);
    int nc = 0;
    if (rare) {
        if (tid == 0) s_cnt = 0;
        __syncthreads();
        #pragma unroll
        for (int i = 0; i < VPT; ++i) {
            uint32_t p4 = (uint32_t)(4 * (i * NT + tid));
            if ((v[i].x & 0x7FFFFFFFu) == T) { int q = atomicAdd(&s_cnt, 1); if (q < 1024) hist[q] = p4 + 0u; }
            if ((v[i].y & 0x7FFFFFFFu) == T) { int q = atomicAdd(&s_cnt, 1); if (q < 1024) hist[q] = p4 + 1u; }
            if ((v[i].z & 0x7FFFFFFFu) == T) { int q = atomicAdd(&s_cnt, 1); if (q < 1024) hist[q] = p4 + 2u; }
            if ((v[i].w & 0x7FFFFFFFu) == T) { int q = atomicAdd(&s_cnt, 1); if (q < 1024) hist[q] = p4 + 3u; }
        }
        __syncthreads();
        nc = s_cnt; if (nc > 1024) nc = 1024;
        for (int t = tid; t < nc; t += NT) {
            uint32_t my = hist[t];
            int rank = 0;
            for (int j = 0; j < nc; ++j) rank += (hist[j] < my) ? 1 : 0;
            hist[1024 + t] = (rank < e) ? 1u : 0u;
        }
        __syncthreads();
    }

    // ---- Phase C: registers -> HBM, threshold + write, 16 B/lane coalesced ----
    auto filt = [&](uint32_t bits, uint32_t idx) -> uint32_t {
        uint32_t key = bits & 0x7FFFFFFFu;
        if (key > T) return bits;
        if (key < T) return 0u;
        if (!rare) return bits;
        for (int j = 0; j < nc; ++j)
            if (hist[j] == idx) return hist[1024 + j] ? bits : 0u;
        return 0u;
    };
    #pragma unroll
    for (int i = 0; i < VPT; ++i) {
        int p = i * NT + tid;
        uint32_t p4 = (uint32_t)(4 * p);
        uint4 o;
        o.x = filt(v[i].x, p4 + 0u);
        o.y = filt(v[i].y, p4 + 1u);
        o.z = filt(v[i].z, p4 + 2u);
        o.w = filt(v[i].w, p4 + 3u);
        outr[p] = o;
    }
}

extern "C" void kernel_launch(void* const* d_in, const int* in_sizes, int n_in,
                              void* d_out, int out_size, void* d_ws, size_t ws_size,
                              hipStream_t stream) {
    const uint32_t* x = (const uint32_t*)d_in[0];
    const int* kptr   = (const int*)d_in[1];
    uint32_t* out     = (uint32_t*)d_out;
    const int rows = in_sizes[0] / ROWLEN;   // 4096 rows of 16384
    topk_abs_kernel<<<rows, NT, 0, stream>>>(x, kptr, out);
}

// Round 4
// 94.843 us; speedup vs baseline: 15.8476x; 1.1568x over previous
//
#include <hip/hip_runtime.h>
#include <stdint.h>

#define ROWLEN 16384
#define NT 512
#define VPT 8   // uint4 per thread: 512 threads * 4 elems * 8 = 16384

typedef uint32_t uint32x4 __attribute__((ext_vector_type(4)));

// Parallel suffix-scan bin select: finds largest bin b with suffix_count(b) >= kk.
// Writes s_bin (bin), s_kk (rank within bin, from top), s_ceq (count in bin).
// All NT threads must call (contains barriers).
template <int NB>
__device__ __forceinline__ void select_bin(const uint32_t* __restrict__ hist,
                                           uint32_t* __restrict__ s_part,
                                           uint32_t* s_bin, int* s_kk, int* s_ceq,
                                           int kk, int tid)
{
    constexpr int C = NB / NT;   // bins per thread (4 for 2048, 2 for 1024)
    uint32_t s = 0;
    #pragma unroll
    for (int j = 0; j < C; ++j) s += hist[tid * C + j];
    s_part[tid] = s;
    __syncthreads();
    if (tid < 64) {              // wave 0: 64 groups of 8 thread-chunks
        uint32_t g = 0;
        #pragma unroll
        for (int j = 0; j < 8; ++j) g += s_part[tid * 8 + j];
        uint32_t S = g;          // suffix-inclusive scan (descending bins = ascending idx)
        #pragma unroll
        for (int off = 1; off < 64; off <<= 1) {
            uint32_t o = __shfl_down(S, off, 64);
            if (tid + off < 64) S += o;
        }
        unsigned long long m = __ballot(S >= (uint32_t)kk);
        int c = 63 - __builtin_clzll(m);                 // crossing group
        uint32_t hv = __shfl(S, (c + 1) & 63, 64);
        uint32_t higher = (c == 63) ? 0u : hv;           // count in groups above c
        if (tid == 0) {
            uint32_t pp[8];
            #pragma unroll
            for (int j = 0; j < 8; ++j) pp[j] = s_part[c * 8 + j];   // independent loads
            int kk2 = kk - (int)higher;
            int cum = 0, j = 7;
            #pragma unroll
            for (int it = 7; it > 0; --it) {
                int cc = (int)pp[j];
                if (cum + cc >= kk2) break;
                cum += cc; --j;
            }
            int tt = c * 8 + j;
            int kk3 = kk2 - cum;
            uint32_t bb[C];
            #pragma unroll
            for (int jj = 0; jj < C; ++jj) bb[jj] = hist[tt * C + jj];
            int cum2 = 0, b = C - 1;
            #pragma unroll
            for (int it = C - 1; it > 0; --it) {
                int cc = (int)bb[b];
                if (cum2 + cc >= kk3) break;
                cum2 += cc; --b;
            }
            *s_bin = (uint32_t)(tt * C + b);
            *s_kk  = kk3 - cum2;
            *s_ceq = (int)bb[b];
        }
    }
    __syncthreads();
}

// __launch_bounds__(512, 6): cap VGPR ~85 so 3 blocks/CU (24 waves) are
// resident — overlaps one row's barrier-heavy selection with another
// row's HBM streaming. (512, 8) would force <=64 VGPR and risk spills.
__global__ __launch_bounds__(NT, 6) void topk_abs_kernel(
    const uint32_t* __restrict__ x, const int* __restrict__ kptr,
    uint32_t* __restrict__ out)
{
    __shared__ uint32_t hist[2048];   // lower 1024: round-1/2 bins, tie idx; upper 1024: candidates, tie flags
    __shared__ uint32_t s_part[NT];
    __shared__ uint32_t s_bin;
    __shared__ int s_kk, s_ceq, s_cnt;

    const int tid = threadIdx.x;
    const uint4* __restrict__ xr  = (const uint4*)(x   + (size_t)blockIdx.x * ROWLEN);
    uint32x4* __restrict__ outr   = (uint32x4*)   (out + (size_t)blockIdx.x * ROWLEN);
    const int k = *kptr;

    // ---- Phase A: HBM -> registers (32 VGPRs), fully coalesced 16 B/lane ----
    uint4 v[VPT];
    #pragma unroll
    for (int i = 0; i < VPT; ++i) v[i] = xr[i * NT + tid];

    // round-0 histogram: 11-bit digit (bits 30:20) over abs bit pattern
    hist[tid] = 0; hist[tid + 512] = 0; hist[tid + 1024] = 0; hist[tid + 1536] = 0;
    __syncthreads();
    #pragma unroll
    for (int i = 0; i < VPT; ++i) {
        atomicAdd(&hist[(v[i].x & 0x7FFFFFFFu) >> 20], 1u);
        atomicAdd(&hist[(v[i].y & 0x7FFFFFFFu) >> 20], 1u);
        atomicAdd(&hist[(v[i].z & 0x7FFFFFFFu) >> 20], 1u);
        atomicAdd(&hist[(v[i].w & 0x7FFFFFFFu) >> 20], 1u);
    }
    __syncthreads();
    select_bin<2048>(hist, s_part, &s_bin, &s_kk, &s_ceq, k, tid);
    const uint32_t b0 = s_bin;
    int kk = s_kk;
    const int ceq0 = s_ceq;

    // clear lower 1024 bins + candidate counter
    hist[tid] = 0; hist[tid + 512] = 0;
    if (tid == 0) s_cnt = 0;
    __syncthreads();

    uint32_t T; int e, ceqT;
    if (ceq0 <= 1024) {
        // ---- candidate path: compact survivors, rounds 1-2 over <=1024 elems ----
        uint32_t* cand = hist + 1024;
        #pragma unroll
        for (int i = 0; i < VPT; ++i) {
            uint32_t a;
            a = v[i].x & 0x7FFFFFFFu; if ((a >> 20) == b0) { cand[atomicAdd(&s_cnt, 1)] = a; atomicAdd(&hist[(a >> 10) & 1023u], 1u); }
            a = v[i].y & 0x7FFFFFFFu; if ((a >> 20) == b0) { cand[atomicAdd(&s_cnt, 1)] = a; atomicAdd(&hist[(a >> 10) & 1023u], 1u); }
            a = v[i].z & 0x7FFFFFFFu; if ((a >> 20) == b0) { cand[atomicAdd(&s_cnt, 1)] = a; atomicAdd(&hist[(a >> 10) & 1023u], 1u); }
            a = v[i].w & 0x7FFFFFFFu; if ((a >> 20) == b0) { cand[atomicAdd(&s_cnt, 1)] = a; atomicAdd(&hist[(a >> 10) & 1023u], 1u); }
        }
        __syncthreads();
        select_bin<1024>(hist, s_part, &s_bin, &s_kk, &s_ceq, kk, tid);
        const uint32_t b1 = s_bin;
        kk = s_kk;
        hist[tid] = 0; hist[tid + 512] = 0;
        __syncthreads();
        for (int t = tid; t < ceq0; t += NT) {
            uint32_t a = cand[t];
            if (((a >> 10) & 1023u) == b1) atomicAdd(&hist[a & 1023u], 1u);
        }
        __syncthreads();
        select_bin<1024>(hist, s_part, &s_bin, &s_kk, &s_ceq, kk, tid);
        T = (b0 << 20) | (b1 << 10) | s_bin;
        e = s_kk; ceqT = s_ceq;
    } else {
        // ---- fallback (pathological skew): full-data rounds from registers ----
        #pragma unroll
        for (int i = 0; i < VPT; ++i) {
            uint32_t a;
            a = v[i].x & 0x7FFFFFFFu; if ((a >> 20) == b0) atomicAdd(&hist[(a >> 10) & 1023u], 1u);
            a = v[i].y & 0x7FFFFFFFu; if ((a >> 20) == b0) atomicAdd(&hist[(a >> 10) & 1023u], 1u);
            a = v[i].z & 0x7FFFFFFFu; if ((a >> 20) == b0) atomicAdd(&hist[(a >> 10) & 1023u], 1u);
            a = v[i].w & 0x7FFFFFFFu; if ((a >> 20) == b0) atomicAdd(&hist[(a >> 10) & 1023u], 1u);
        }
        __syncthreads();
        select_bin<1024>(hist, s_part, &s_bin, &s_kk, &s_ceq, kk, tid);
        const uint32_t b1 = s_bin;
        kk = s_kk;
        hist[tid] = 0; hist[tid + 512] = 0;
        __syncthreads();
        const uint32_t pfx = (b0 << 10) | b1;
        #pragma unroll
        for (int i = 0; i < VPT; ++i) {
            uint32_t a;
            a = v[i].x & 0x7FFFFFFFu; if ((a >> 10) == pfx) atomicAdd(&hist[a & 1023u], 1u);
            a = v[i].y & 0x7FFFFFFFu; if ((a >> 10) == pfx) atomicAdd(&hist[a & 1023u], 1u);
            a = v[i].z & 0x7FFFFFFFu; if ((a >> 10) == pfx) atomicAdd(&hist[a & 1023u], 1u);
            a = v[i].w & 0x7FFFFFFFu; if ((a >> 10) == pfx) atomicAdd(&hist[a & 1023u], 1u);
        }
        __syncthreads();
        select_bin<1024>(hist, s_part, &s_bin, &s_kk, &s_ceq, kk, tid);
        T = (b0 << 20) | (b1 << 10) | s_bin;
        e = s_kk; ceqT = s_ceq;
    }

    // ---- tie at the cutoff (≈never on random data): lowest-index-first ----
    const bool rare = (ceqT != e);
    int nc = 0;
    if (rare) {
        if (tid == 0) s_cnt = 0;
        __syncthreads();
        #pragma unroll
        for (int i = 0; i < VPT; ++i) {
            uint32_t p4 = (uint32_t)(4 * (i * NT + tid));
            if ((v[i].x & 0x7FFFFFFFu) == T) { int q = atomicAdd(&s_cnt, 1); if (q < 1024) hist[q] = p4 + 0u; }
            if ((v[i].y & 0x7FFFFFFFu) == T) { int q = atomicAdd(&s_cnt, 1); if (q < 1024) hist[q] = p4 + 1u; }
            if ((v[i].z & 0x7FFFFFFFu) == T) { int q = atomicAdd(&s_cnt, 1); if (q < 1024) hist[q] = p4 + 2u; }
            if ((v[i].w & 0x7FFFFFFFu) == T) { int q = atomicAdd(&s_cnt, 1); if (q < 1024) hist[q] = p4 + 3u; }
        }
        __syncthreads();
        nc = s_cnt; if (nc > 1024) nc = 1024;
        for (int t = tid; t < nc; t += NT) {
            uint32_t my = hist[t];
            int rank = 0;
            for (int j = 0; j < nc; ++j) rank += (hist[j] < my) ? 1 : 0;
            hist[1024 + t] = (rank < e) ? 1u : 0u;
        }
        __syncthreads();
    }

    // ---- Phase C: registers -> HBM, nontemporal (output never re-read;
    // avoids write-allocate evicting the input from L3 between replays) ----
    auto filt = [&](uint32_t bits, uint32_t idx) -> uint32_t {
        uint32_t key = bits & 0x7FFFFFFFu;
        if (key > T) return bits;
        if (key < T) return 0u;
        if (!rare) return bits;
        for (int j = 0; j < nc; ++j)
            if (hist[j] == idx) return hist[1024 + j] ? bits : 0u;
        return 0u;
    };
    #pragma unroll
    for (int i = 0; i < VPT; ++i) {
        int p = i * NT + tid;
        uint32_t p4 = (uint32_t)(4 * p);
        uint32x4 o;
        o.x = filt(v[i].x, p4 + 0u);
        o.y = filt(v[i].y, p4 + 1u);
        o.z = filt(v[i].z, p4 + 2u);
        o.w = filt(v[i].w, p4 + 3u);
        __builtin_nontemporal_store(o, &outr[p]);
    }
}

extern "C" void kernel_launch(void* const* d_in, const int* in_sizes, int n_in,
                              void* d_out, int out_size, void* d_ws, size_t ws_size,
                              hipStream_t stream) {
    const uint32_t* x = (const uint32_t*)d_in[0];
    const int* kptr   = (const int*)d_in[1];
    uint32_t* out     = (uint32_t*)d_out;
    const int rows = in_sizes[0] / ROWLEN;   // 4096 rows of 16384
    topk_abs_kernel<<<rows, NT, 0, stream>>>(x, kptr, out);
}